// Round 2
// 236.859 us; speedup vs baseline: 1.0504x; 1.0504x over previous
//
#include <hip/hip_runtime.h>
#include <hip/hip_bf16.h>

// ---- types ----
typedef __bf16 bf16x8 __attribute__((ext_vector_type(8)));
typedef __bf16 bf16x4 __attribute__((ext_vector_type(4)));
typedef float  f32x4  __attribute__((ext_vector_type(4)));

#define MFMA16(a, b, c) __builtin_amdgcn_mfma_f32_16x16x32_bf16((a), (b), (c), 0, 0, 0)

// Problem constants
#define BATCH 16
#define SEQ   1024
#define VD    1024
#define TD    768
#define HDIM  512
#define MROWS (BATCH * SEQ)   // 16384

typedef __attribute__((address_space(1))) const unsigned int gas_uint;
typedef __attribute__((address_space(3))) unsigned int las_uint;

__device__ __forceinline__ void async_copy16(const void* g, void* l) {
    // global -> LDS DMA, 16B/lane; LDS dest = wave-uniform base + lane*16
    __builtin_amdgcn_global_load_lds((gas_uint*)g, (las_uint*)l, 16, 0, 0);
}

// ---------------------------------------------------------------------------
// Stage one 128x64 bf16 tile (1024 x 16B chunks, 256 threads) via DMA with
// chunk-XOR swizzle applied on the GLOBAL side (LDS side stays lane-linear).
// Row r holds its 8 chunks in slots permuted by r&7.
// ---------------------------------------------------------------------------
__device__ __forceinline__ void stage_tile_bf16(const __bf16* __restrict__ src,
                                                size_t ld, int row0, int k0,
                                                __bf16* __restrict__ buf, int tid) {
#pragma unroll
    for (int i = 0; i < 4; ++i) {
        const int c = i * 256 + tid;          // chunk slot 0..1023
        const int r = c >> 3;                 // row 0..127
        const int g = (c & 7) ^ (r & 7);      // swizzled global chunk
        async_copy16(&src[(size_t)(row0 + r) * ld + k0 + g * 8],
                     &buf[(c & ~63) * 8]);
    }
}

// Same pattern, 256x64 tile with 512 threads (2048 chunks, 4/thread).
__device__ __forceinline__ void stage_tile256(const __bf16* __restrict__ src,
                                              size_t ld, int row0, int k0,
                                              __bf16* __restrict__ buf, int tid) {
#pragma unroll
    for (int i = 0; i < 4; ++i) {
        const int c = i * 512 + tid;          // chunk slot 0..2047
        const int r = c >> 3;                 // row 0..255
        const int g = (c & 7) ^ (r & 7);      // swizzled global chunk
        async_copy16(&src[(size_t)(row0 + r) * ld + k0 + g * 8],
                     &buf[(c & ~63) * 8]);
    }
}

// fragment read: row r, k-half h (0/1), quad fq -> chunk (h*4+fq)^(r&7)
__device__ __forceinline__ bf16x8 frag_read(const __bf16* __restrict__ buf,
                                            int r, int h, int fq) {
    return *reinterpret_cast<const bf16x8*>(&buf[(r * 8 + ((h * 4 + fq) ^ (r & 7))) * 8]);
}

// ---------------------------------------------------------------------------
// Convert Xv, Xt, Wv, Wt fp32 -> bf16 in one streaming pass (~168 MB).
// ---------------------------------------------------------------------------
#define NC_XV (BATCH * SEQ * VD / 4)   // 4194304
#define NC_XT (BATCH * SEQ * TD / 4)   // 3145728
#define NC_WV (HDIM * VD / 4)          // 131072
#define NC_WT (HDIM * TD / 4)          // 98304
#define NC_TOTAL (NC_XV + NC_XT + NC_WV + NC_WT)

__global__ __launch_bounds__(256) void conv_kernel(
    const float* __restrict__ Xv, const float* __restrict__ Xt,
    const float* __restrict__ Wv, const float* __restrict__ Wt,
    __bf16* __restrict__ Xvb, __bf16* __restrict__ Xtb,
    __bf16* __restrict__ Wvb, __bf16* __restrict__ Wtb) {
    int i = blockIdx.x * 256 + threadIdx.x;
    if (i >= NC_TOTAL) return;
    const float* src;
    __bf16* dst;
    if (i < NC_XV)                     { src = Xv; dst = Xvb; }
    else if ((i -= NC_XV) < NC_XT)     { src = Xt; dst = Xtb; }
    else if ((i -= NC_XT) < NC_WV)     { src = Wv; dst = Wvb; }
    else { i -= NC_WV;                   src = Wt; dst = Wtb; }
    const float4 x = reinterpret_cast<const float4*>(src)[i];
    bf16x4 p = {(__bf16)x.x, (__bf16)x.y, (__bf16)x.z, (__bf16)x.w};
    reinterpret_cast<bf16x4*>(dst)[i] = p;
}

// ---------------------------------------------------------------------------
// Projection GEMM (NT), all-bf16, BK=64, DMA-prefetch double-buffer:
//   C[M][512] = X[M][K] * W[512][K]^T + bias -> bf16, + fused row-norm^2.
// 128x128 tile, 256 threads (4 waves 2x2, wave 64x64, 4x4 MFMA 16x16x32).
// ---------------------------------------------------------------------------
__global__ __launch_bounds__(256) void proj_kernel(
    const __bf16* __restrict__ Xvb, const __bf16* __restrict__ Wvb, const float* __restrict__ bv_,
    const __bf16* __restrict__ Xtb, const __bf16* __restrict__ Wtb, const float* __restrict__ bt_,
    __bf16* __restrict__ vout, __bf16* __restrict__ tout,
    float* __restrict__ vn2, float* __restrict__ tn2)
{
    // L = mlow + 8*( n + 4*( mhigh + 16*z ) ) -> same-m n-tiles share an XCD
    const int L     = blockIdx.x;
    const int mlow  = L & 7;
    const int n     = (L >> 3) & 3;
    const int mhigh = (L >> 5) & 15;
    const int z     = L >> 9;
    const int m0    = (mhigh * 8 + mlow) * 128;
    const int n0    = n * 128;

    const __bf16* X; const __bf16* Wb; const float* bias; __bf16* out; float* n2; int K;
    if (z == 0) { X = Xvb; Wb = Wvb; bias = bv_; out = vout; n2 = vn2; K = VD; }
    else        { X = Xtb; Wb = Wtb; bias = bt_; out = tout; n2 = tn2; K = TD; }

    __shared__ __bf16 As[2][128 * 64];
    __shared__ __bf16 Bs[2][128 * 64];

    const int tid  = threadIdx.x;
    const int lane = tid & 63;
    const int wave = tid >> 6;
    const int wr   = wave >> 1;
    const int wc   = wave & 1;
    const int fr   = lane & 15;
    const int fq   = lane >> 4;

    f32x4 acc[4][4] = {};
    const int nk = K >> 6;   // 16 (v) / 12 (t)

    // prologue: stage tile 0
    stage_tile_bf16(X,  K, m0, 0, As[0], tid);
    stage_tile_bf16(Wb, K, n0, 0, Bs[0], tid);
    __syncthreads();

    for (int ki = 0; ki < nk; ++ki) {
        // prefetch tile k+1 (DMA overlaps the compute below)
        if (ki + 1 < nk) {
            const int kk = (ki + 1) << 6;
            stage_tile_bf16(X,  K, m0, kk, As[(ki + 1) & 1], tid);
            stage_tile_bf16(Wb, K, n0, kk, Bs[(ki + 1) & 1], tid);
        }
        const __bf16* Ab = As[ki & 1];
        const __bf16* Bb = Bs[ki & 1];
#pragma unroll
        for (int h = 0; h < 2; ++h) {
            bf16x8 a[4], b[4];
#pragma unroll
            for (int tm = 0; tm < 4; ++tm)
                a[tm] = frag_read(Ab, wr * 64 + tm * 16 + fr, h, fq);
#pragma unroll
            for (int tn = 0; tn < 4; ++tn)
                b[tn] = frag_read(Bb, wc * 64 + tn * 16 + fr, h, fq);
#pragma unroll
            for (int tm = 0; tm < 4; ++tm)
#pragma unroll
                for (int tn = 0; tn < 4; ++tn)
                    acc[tm][tn] = MFMA16(a[tm], b[tn], acc[tm][tn]);
        }
        __syncthreads();
    }

    // epilogue: +bias, bf16 store, fused partial row-norm^2
    float bc[4];
#pragma unroll
    for (int tn = 0; tn < 4; ++tn)
        bc[tn] = bias[n0 + wc * 64 + tn * 16 + fr];

#pragma unroll
    for (int tm = 0; tm < 4; ++tm) {
        const int rowb = m0 + wr * 64 + tm * 16 + fq * 4;
#pragma unroll
        for (int r = 0; r < 4; ++r) {
            float s = 0.f;
#pragma unroll
            for (int tn = 0; tn < 4; ++tn) {
                const float e = acc[tm][tn][r] + bc[tn];
                out[(size_t)(rowb + r) * HDIM + n0 + wc * 64 + tn * 16 + fr] = (__bf16)e;
                s = fmaf(e, e, s);
            }
            s += __shfl_xor(s, 1);
            s += __shfl_xor(s, 2);
            s += __shfl_xor(s, 4);
            s += __shfl_xor(s, 8);
            if (fr == 0) atomicAdd(&n2[rowb + r], s);
        }
    }
}

// ---------------------------------------------------------------------------
// Batched dots GEMM (NT) -- 256x256 tile, 512 threads (8 waves 2x4, wave
// 128x64), BK=64, K=512 -> 8 K-tiles, double-buffered DMA staging with
// COUNTED vmcnt (T4) + 4-phase MFMA split + setprio (T3/T5) + raw s_barrier
// only (no __syncthreads -> no compiler vmcnt(0) drain).
//   out[b][i][j] = v.t / max(sqrt(vn2_i*tn2_j), eps)
// Grid: 256 blocks = 1/CU; XCD x owns batches {2x, 2x+1} (4MB = its L2).
// Barrier-divergence audit: every s_barrier is in block-uniform control flow
// (NKT, q, kt guards are uniform) -> all 8 waves hit identical barrier counts.
// ---------------------------------------------------------------------------
__global__ __launch_bounds__(512, 2) void dots_kernel(const __bf16* __restrict__ v,
                                                      const __bf16* __restrict__ t,
                                                      const float* __restrict__ vn2,
                                                      const float* __restrict__ tn2,
                                                      float* __restrict__ out) {
    __shared__ __bf16 As[2][256 * 64];   // 64 KiB
    __shared__ __bf16 Bs[2][256 * 64];   // 64 KiB

    // blockIdx round-robins XCDs: x = L&7. XCD x gets batches 2x, 2x+1.
    const int L  = blockIdx.x;
    const int x  = L & 7;
    const int s  = L >> 3;               // 0..31 within XCD
    const int b  = x * 2 + (s >> 4);     // batch
    const int i0 = ((s >> 2) & 3) * 256;
    const int j0 = (s & 3) * 256;

    const __bf16* vb = v + (size_t)b * SEQ * HDIM;
    const __bf16* tb = t + (size_t)b * SEQ * HDIM;

    const int tid  = threadIdx.x;
    const int lane = tid & 63;
    const int wave = tid >> 6;
    const int wr   = wave >> 2;          // 0..1  (128-row half)
    const int wc   = wave & 3;           // 0..3  (64-col quarter)
    const int fr   = lane & 15;
    const int fq   = lane >> 4;

    f32x4 acc[8][4] = {};
    const int NKT = HDIM >> 6;           // 8

    // prologue: stage K-tiles 0 and 1 (8 DMA loads/thread each)
    stage_tile256(vb, HDIM, i0, 0,  As[0], tid);
    stage_tile256(tb, HDIM, j0, 0,  Bs[0], tid);
    stage_tile256(vb, HDIM, i0, 64, As[1], tid);
    stage_tile256(tb, HDIM, j0, 64, Bs[1], tid);
    asm volatile("s_waitcnt vmcnt(8)" ::: "memory");  // K-tile 0 landed (in-order retire)
    __builtin_amdgcn_s_barrier();                     // all waves' tile-0 loads drained

    for (int kt = 0; kt < NKT; ++kt) {
        const __bf16* Ab = As[kt & 1];
        const __bf16* Bb = Bs[kt & 1];
        bf16x8 bfr[4][2];                // B frags live across all 4 phases
#pragma unroll
        for (int q = 0; q < 4; ++q) {    // phase q: m-frags {2q, 2q+1} x 4n x 2kh = 16 MFMA
            bf16x8 afr[2][2];
#pragma unroll
            for (int m2 = 0; m2 < 2; ++m2)
#pragma unroll
                for (int h = 0; h < 2; ++h)
                    afr[m2][h] = frag_read(Ab, wr * 128 + (q * 2 + m2) * 16 + fr, h, fq);
            if (q == 0) {
#pragma unroll
                for (int n = 0; n < 4; ++n)
#pragma unroll
                    for (int h = 0; h < 2; ++h)
                        bfr[n][h] = frag_read(Bb, wc * 64 + n * 16 + fr, h, fq);
            }
            __builtin_amdgcn_s_barrier();           // phase-entry lockstep
            __builtin_amdgcn_s_setprio(1);
#pragma unroll
            for (int h = 0; h < 2; ++h)
#pragma unroll
                for (int m2 = 0; m2 < 2; ++m2)
#pragma unroll
                    for (int n = 0; n < 4; ++n)
                        acc[q * 2 + m2][n] = MFMA16(afr[m2][h], bfr[n][h], acc[q * 2 + m2][n]);
            __builtin_amdgcn_s_setprio(0);
        }
        // K-tile boundary: buf[kt&1] fully consumed by ALL waves after this barrier.
        if (kt < NKT - 1) {
            __builtin_amdgcn_s_barrier();           // end of reads of buf[kt&1]
            __builtin_amdgcn_sched_barrier(0);
            if (kt + 2 < NKT) {
                const int kk = (kt + 2) << 6;
                stage_tile256(vb, HDIM, i0, kk, As[kt & 1], tid);
                stage_tile256(tb, HDIM, j0, kk, Bs[kt & 1], tid);
                // outstanding: stage(kt+1)=8 (oldest) + stage(kt+2)=8.
                // Leave kt+2 in flight across the whole next K-tile (T4).
                asm volatile("s_waitcnt vmcnt(8)" ::: "memory");
            } else {
                asm volatile("s_waitcnt vmcnt(0)" ::: "memory");
            }
            __builtin_amdgcn_sched_barrier(0);
            __builtin_amdgcn_s_barrier();           // all waves drained kt+1
        }
    }

    // epilogue: normalize and store fp32 output
    float vr2[8][4];
#pragma unroll
    for (int mf = 0; mf < 8; ++mf)
#pragma unroll
        for (int r = 0; r < 4; ++r)
            vr2[mf][r] = vn2[b * SEQ + i0 + wr * 128 + mf * 16 + fq * 4 + r];

    float* outb = out + ((size_t)b << 20);
#pragma unroll
    for (int n = 0; n < 4; ++n) {
        const int j     = j0 + wc * 64 + n * 16 + fr;
        const float tj2 = tn2[b * SEQ + j];
#pragma unroll
        for (int mf = 0; mf < 8; ++mf) {
            const int ib = i0 + wr * 128 + mf * 16 + fq * 4;
#pragma unroll
            for (int r = 0; r < 4; ++r) {
                const float denom = fmaxf(sqrtf(vr2[mf][r] * tj2), 1e-8f);
                outb[(size_t)(ib + r) * SEQ + j] = acc[mf][n][r] * __builtin_amdgcn_rcpf(denom);
            }
        }
    }
}

// ---------------------------------------------------------------------------
extern "C" void kernel_launch(void* const* d_in, const int* in_sizes, int n_in,
                              void* d_out, int out_size, void* d_ws, size_t ws_size,
                              hipStream_t stream) {
    const float* Xv = (const float*)d_in[0];
    const float* Xt = (const float*)d_in[1];
    const float* Wv = (const float*)d_in[2];
    const float* bv = (const float*)d_in[3];
    const float* Wt = (const float*)d_in[4];
    const float* bt = (const float*)d_in[5];
    float* out = (float*)d_out;

    char* ws = (char*)d_ws;
    size_t off = 0;
    __bf16* v   = (__bf16*)(ws + off); off += (size_t)MROWS * HDIM * 2;    // 16 MiB
    __bf16* t   = (__bf16*)(ws + off); off += (size_t)MROWS * HDIM * 2;    // 16 MiB
    __bf16* Xvb = (__bf16*)(ws + off); off += (size_t)MROWS * VD * 2;      // 32 MiB
    __bf16* Xtb = (__bf16*)(ws + off); off += (size_t)MROWS * TD * 2;      // 24 MiB
    __bf16* Wvb = (__bf16*)(ws + off); off += (size_t)HDIM * VD * 2;       // 1 MiB
    __bf16* Wtb = (__bf16*)(ws + off); off += (size_t)HDIM * TD * 2;       // 0.75 MiB
    float*  vn2 = (float*)(ws + off);  off += (size_t)MROWS * 4;           // 64 KiB
    float*  tn2 = (float*)(ws + off);  off += (size_t)MROWS * 4;           // 64 KiB

    hipMemsetAsync(vn2, 0, (size_t)2 * MROWS * 4, stream);

    // 0) fp32 -> bf16 streaming convert (X and W)
    conv_kernel<<<(NC_TOTAL + 255) / 256, 256, 0, stream>>>(Xv, Xt, Wv, Wt, Xvb, Xtb, Wvb, Wtb);

    // 1) projections + fused norms: 1024 swizzled blocks (512 v + 512 t)
    proj_kernel<<<1024, 256, 0, stream>>>(Xvb, Wvb, bv, Xtb, Wtb, bt, v, t, vn2, tn2);

    // 2) batched dots + normalize: 256 swizzled blocks of 512 threads
    dots_kernel<<<256, 512, 0, stream>>>(v, t, vn2, tn2, out);
}